// Round 6
// baseline (609.130 us; speedup 1.0000x reference)
//
#include <hip/hip_runtime.h>
#include <hip/hip_fp16.h>

// GCN 2-layer. Pipeline:
//   blkhist -> offsets (decoupled, atomic-free) -> scatter2 (LDS cursors)
//   -> per-bucket LDS counting sort -> gemm1 -> gather-agg1 -> gemm2 -> gather-agg2
// R5 post-mortem: agg1 is gather-BW bound (FETCH 271 MB, 3.6 TB/s, VALU 21%).
// This round: fp16 storage for all gathered tables (hs/h1/gs) halves gather
// bytes; fp32 accumulation keeps error at ~5e-4 rel per message.

#define BSHIFT 8
#define BNODES 256
#define NB 256  // partition blocks

union H8 {  // 8 fp16 = 16 B
    uint4 u;
    __half2 h[4];
};

// Per-block bucket histogram: blkcnt[bin*NB + blk].
__global__ __launch_bounds__(256) void blkhist_kernel(
    const int* __restrict__ dst, int E, int* __restrict__ blkcnt, int B) {
    __shared__ int h[512];
    int t = threadIdx.x, b = blockIdx.x;
    for (int i = t; i < 512; i += 256) h[i] = 0;
    __syncthreads();
    int per = (E + NB - 1) / NB;
    int lo = b * per;
    int hi = min(lo + per, E);
    for (int i = lo + t; i < hi; i += 256) atomicAdd(&h[dst[i] >> BSHIFT], 1);
    __syncthreads();
    for (int i = t; i < B; i += 256) blkcnt[i * NB + b] = h[i];
}

// One block: in-place per-bucket exclusive scan across NB blocks, then
// exclusive scan of bucket totals -> base[]. Also off[N]=E, base[B]=E.
__global__ __launch_bounds__(512) void offsets_kernel(
    int* __restrict__ blkcnt, int* __restrict__ base, int* __restrict__ off,
    int B, int E, int N) {
    __shared__ int s[512];
    int t = threadIdx.x;
    int tot = 0;
    if (t < B) {
        int* row = blkcnt + (size_t)t * NB;
        int run = 0;
#pragma unroll 4
        for (int b = 0; b < NB; b++) {
            int c = row[b];
            row[b] = run;  // within-bucket block-exclusive prefix
            run += c;
        }
        tot = run;
    }
    s[t] = tot;
    __syncthreads();
#pragma unroll
    for (int d = 1; d < 512; d <<= 1) {
        int v = (t >= d) ? s[t - d] : 0;
        __syncthreads();
        s[t] += v;
        __syncthreads();
    }
    if (t < B) base[t] = s[t] - tot;  // bucket-exclusive prefix
    if (t == 0) {
        base[B] = E;
        off[N] = E;
    }
}

// Scatter via LDS cursors seeded from precomputed bases. No global atomics.
__global__ __launch_bounds__(256) void scatter2_kernel(
    const int* __restrict__ src, const int* __restrict__ dst,
    const int* __restrict__ blkcnt, const int* __restrict__ base,
    int* __restrict__ packed, int E, int B) {
    __shared__ int cur[512];
    int t = threadIdx.x, b = blockIdx.x;
    for (int i = t; i < B; i += 256) cur[i] = base[i] + blkcnt[i * NB + b];
    __syncthreads();
    int per = (E + NB - 1) / NB;
    int lo = b * per;
    int hi = min(lo + per, E);
    for (int i = lo + t; i < hi; i += 256) {
        int d = dst[i];
        int pos = atomicAdd(&cur[d >> BSHIFT], 1);
        packed[pos] = (src[i] << BSHIFT) | (d & (BNODES - 1));
    }
}

// Per-bucket LDS counting sort -> ssrc grouped by node; also off & dinv.
__global__ __launch_bounds__(256) void bsort_kernel(
    const int* __restrict__ packed, const int* __restrict__ base,
    int* __restrict__ ssrc, int* __restrict__ off, float* __restrict__ dinv,
    int N) {
    __shared__ int s[BNODES];
    __shared__ int cur[BNODES];
    int t = threadIdx.x, b = blockIdx.x;
    s[t] = 0;
    __syncthreads();
    int lo = base[b], hi = base[b + 1];
    for (int i = lo + t; i < hi; i += 256)
        atomicAdd(&s[packed[i] & (BNODES - 1)], 1);
    __syncthreads();
    int deg = s[t];
    __syncthreads();
    s[t] = deg;
    __syncthreads();
#pragma unroll
    for (int d = 1; d < BNODES; d <<= 1) {
        int v = (t >= d) ? s[t - d] : 0;
        __syncthreads();
        s[t] += v;
        __syncthreads();
    }
    int excl = s[t] - deg;
    cur[t] = excl;
    int node = (b << BSHIFT) + t;
    if (node < N) {
        off[node] = lo + excl;
        dinv[node] = rsqrtf((float)(deg + 1));
    }
    __syncthreads();
    for (int i = lo + t; i < hi; i += 256) {
        int p = packed[i];
        int pos = atomicAdd(&cur[p & (BNODES - 1)], 1);
        ssrc[lo + pos] = p >> BSHIFT;
    }
}

// hsh = fp16((x@W1)*dinv). 2 rows/thread, W1 broadcast from LDS.
__global__ __launch_bounds__(256) void gemm1_kernel(
    const float* __restrict__ x, const float* __restrict__ W1,
    const float* __restrict__ dinv, __half* __restrict__ hsh, int N) {
    __shared__ float4 Ws[64 * 16];
    int t = threadIdx.x;
    const float4* W4 = (const float4*)W1;
    for (int i = t; i < 1024; i += 256) Ws[i] = W4[i];
    __syncthreads();
    int ra = blockIdx.x * 512 + t;
    int rb = ra + 256;
    if (ra >= N) return;
    bool hb = rb < N;
    const float4* xa = (const float4*)(x + (size_t)ra * 64);
    const float4* xb = (const float4*)(x + (size_t)rb * 64);
    float4 acc0[16], acc1[16];
#pragma unroll
    for (int j = 0; j < 16; j++) {
        acc0[j] = make_float4(0.f, 0.f, 0.f, 0.f);
        acc1[j] = make_float4(0.f, 0.f, 0.f, 0.f);
    }
    for (int k4 = 0; k4 < 16; k4++) {
        float4 x0 = xa[k4];
        float4 x1 = hb ? xb[k4] : make_float4(0.f, 0.f, 0.f, 0.f);
#pragma unroll
        for (int kk = 0; kk < 4; kk++) {
            float a0 = ((const float*)&x0)[kk];
            float a1 = ((const float*)&x1)[kk];
            const float4* wr = &Ws[(k4 * 4 + kk) * 16];
#pragma unroll
            for (int j = 0; j < 16; j++) {
                float4 w = wr[j];
                acc0[j].x += a0 * w.x; acc0[j].y += a0 * w.y;
                acc0[j].z += a0 * w.z; acc0[j].w += a0 * w.w;
                acc1[j].x += a1 * w.x; acc1[j].y += a1 * w.y;
                acc1[j].z += a1 * w.z; acc1[j].w += a1 * w.w;
            }
        }
    }
    float d0 = dinv[ra];
    uint4* ha = (uint4*)(hsh + (size_t)ra * 64);
#pragma unroll
    for (int j = 0; j < 8; j++) {
        H8 p;
        float4 v0 = acc0[2 * j], v1 = acc0[2 * j + 1];
        p.h[0] = __floats2half2_rn(v0.x * d0, v0.y * d0);
        p.h[1] = __floats2half2_rn(v0.z * d0, v0.w * d0);
        p.h[2] = __floats2half2_rn(v1.x * d0, v1.y * d0);
        p.h[3] = __floats2half2_rn(v1.z * d0, v1.w * d0);
        ha[j] = p.u;
    }
    if (hb) {
        float d1 = dinv[rb];
        uint4* hbp = (uint4*)(hsh + (size_t)rb * 64);
#pragma unroll
        for (int j = 0; j < 8; j++) {
            H8 p;
            float4 v0 = acc1[2 * j], v1 = acc1[2 * j + 1];
            p.h[0] = __floats2half2_rn(v0.x * d1, v0.y * d1);
            p.h[1] = __floats2half2_rn(v0.z * d1, v0.w * d1);
            p.h[2] = __floats2half2_rn(v1.x * d1, v1.y * d1);
            p.h[3] = __floats2half2_rn(v1.z * d1, v1.w * d1);
            hbp[j] = p.u;
        }
    }
}

// Gather-aggregate layer 1: wave per node, lane = feature (64). fp16 gathers,
// fp32 accumulate. h1h = fp16(relu(acc*dinv + b1)).
__global__ __launch_bounds__(256) void agg1_kernel(
    const __half* __restrict__ hsh, const int* __restrict__ ssrc,
    const int* __restrict__ off, const float* __restrict__ dinv,
    const float* __restrict__ b1, __half* __restrict__ h1h, int N) {
    int w = (blockIdx.x * 256 + threadIdx.x) >> 6;
    int l = threadIdx.x & 63;
    if (w >= N) return;
    float acc = __half2float(hsh[(size_t)w * 64 + l]);  // self-loop
    int lo = off[w], hi = off[w + 1];
    int e = lo;
    for (; e + 4 <= hi; e += 4) {
        int s0 = ssrc[e + 0];
        int s1 = ssrc[e + 1];
        int s2 = ssrc[e + 2];
        int s3 = ssrc[e + 3];
        float v0 = __half2float(hsh[(size_t)s0 * 64 + l]);
        float v1 = __half2float(hsh[(size_t)s1 * 64 + l]);
        float v2 = __half2float(hsh[(size_t)s2 * 64 + l]);
        float v3 = __half2float(hsh[(size_t)s3 * 64 + l]);
        acc += (v0 + v1) + (v2 + v3);
    }
    for (; e < hi; e++) {
        int s = ssrc[e];
        acc += __half2float(hsh[(size_t)s * 64 + l]);
    }
    float r = fmaxf(acc * dinv[w] + b1[l], 0.f);
    h1h[(size_t)w * 64 + l] = __float2half_rn(r);
}

// gsh = fp16((h1@W2)*dinv). 2 rows/thread, fp16 input rows.
__global__ __launch_bounds__(256) void gemm2_kernel(
    const __half* __restrict__ h1h, const float* __restrict__ W2,
    const float* __restrict__ dinv, __half* __restrict__ gsh, int N) {
    __shared__ float4 Ws[64 * 8];
    int t = threadIdx.x;
    const float4* W4 = (const float4*)W2;
    for (int i = t; i < 512; i += 256) Ws[i] = W4[i];
    __syncthreads();
    int ra = blockIdx.x * 512 + t;
    int rb = ra + 256;
    if (ra >= N) return;
    bool hb = rb < N;
    const uint4* xa = (const uint4*)(h1h + (size_t)ra * 64);
    const uint4* xb = (const uint4*)(h1h + (size_t)rb * 64);
    H8 raw0[8], raw1[8];
#pragma unroll
    for (int j = 0; j < 8; j++) {
        raw0[j].u = xa[j];
        raw1[j].u = hb ? xb[j] : make_uint4(0, 0, 0, 0);
    }
    float4 acc0[8], acc1[8];
#pragma unroll
    for (int j = 0; j < 8; j++) {
        acc0[j] = make_float4(0.f, 0.f, 0.f, 0.f);
        acc1[j] = make_float4(0.f, 0.f, 0.f, 0.f);
    }
#pragma unroll
    for (int k2 = 0; k2 < 32; k2++) {  // half2 steps: feats 2k2, 2k2+1
        float2 f0 = __half22float2(raw0[k2 >> 2].h[k2 & 3]);
        float2 f1 = __half22float2(raw1[k2 >> 2].h[k2 & 3]);
#pragma unroll
        for (int kk = 0; kk < 2; kk++) {
            float a0 = kk ? f0.y : f0.x;
            float a1 = kk ? f1.y : f1.x;
            const float4* wr = &Ws[(k2 * 2 + kk) * 8];
#pragma unroll
            for (int j = 0; j < 8; j++) {
                float4 w = wr[j];
                acc0[j].x += a0 * w.x; acc0[j].y += a0 * w.y;
                acc0[j].z += a0 * w.z; acc0[j].w += a0 * w.w;
                acc1[j].x += a1 * w.x; acc1[j].y += a1 * w.y;
                acc1[j].z += a1 * w.z; acc1[j].w += a1 * w.w;
            }
        }
    }
    float d0 = dinv[ra];
    uint4* ga = (uint4*)(gsh + (size_t)ra * 32);
#pragma unroll
    for (int j = 0; j < 4; j++) {
        H8 p;
        float4 v0 = acc0[2 * j], v1 = acc0[2 * j + 1];
        p.h[0] = __floats2half2_rn(v0.x * d0, v0.y * d0);
        p.h[1] = __floats2half2_rn(v0.z * d0, v0.w * d0);
        p.h[2] = __floats2half2_rn(v1.x * d0, v1.y * d0);
        p.h[3] = __floats2half2_rn(v1.z * d0, v1.w * d0);
        ga[j] = p.u;
    }
    if (hb) {
        float d1 = dinv[rb];
        uint4* gb = (uint4*)(gsh + (size_t)rb * 32);
#pragma unroll
        for (int j = 0; j < 4; j++) {
            H8 p;
            float4 v0 = acc1[2 * j], v1 = acc1[2 * j + 1];
            p.h[0] = __floats2half2_rn(v0.x * d1, v0.y * d1);
            p.h[1] = __floats2half2_rn(v0.z * d1, v0.w * d1);
            p.h[2] = __floats2half2_rn(v1.x * d1, v1.y * d1);
            p.h[3] = __floats2half2_rn(v1.z * d1, v1.w * d1);
            gb[j] = p.u;
        }
    }
}

// Gather-aggregate layer 2: half-wave per node, lane = feature (32).
__global__ __launch_bounds__(256) void agg2_kernel(
    const __half* __restrict__ gsh, const int* __restrict__ ssrc,
    const int* __restrict__ off, const float* __restrict__ dinv,
    const float* __restrict__ b2, float* __restrict__ out, int N) {
    int w = (blockIdx.x * 256 + threadIdx.x) >> 5;
    int l = threadIdx.x & 31;
    if (w >= N) return;
    float acc = __half2float(gsh[(size_t)w * 32 + l]);  // self-loop
    int lo = off[w], hi = off[w + 1];
    int e = lo;
    for (; e + 4 <= hi; e += 4) {
        int s0 = ssrc[e + 0];
        int s1 = ssrc[e + 1];
        int s2 = ssrc[e + 2];
        int s3 = ssrc[e + 3];
        float v0 = __half2float(gsh[(size_t)s0 * 32 + l]);
        float v1 = __half2float(gsh[(size_t)s1 * 32 + l]);
        float v2 = __half2float(gsh[(size_t)s2 * 32 + l]);
        float v3 = __half2float(gsh[(size_t)s3 * 32 + l]);
        acc += (v0 + v1) + (v2 + v3);
    }
    for (; e < hi; e++) {
        int s = ssrc[e];
        acc += __half2float(gsh[(size_t)s * 32 + l]);
    }
    out[(size_t)w * 32 + l] = acc * dinv[w] + b2[l];
}

extern "C" void kernel_launch(void* const* d_in, const int* in_sizes, int n_in,
                              void* d_out, int out_size, void* d_ws,
                              size_t ws_size, hipStream_t stream) {
    const float* x  = (const float*)d_in[0];
    const int* ei   = (const int*)d_in[1];
    const float* W1 = (const float*)d_in[2];
    const float* b1 = (const float*)d_in[3];
    const float* W2 = (const float*)d_in[4];
    const float* b2 = (const float*)d_in[5];
    int N = in_sizes[0] / 64;
    int E = in_sizes[1] / 2;
    const int* src = ei;
    const int* dst = ei + E;
    int B = (N + BNODES - 1) >> BSHIFT;  // 391 for N=100000

    char* ws = (char*)d_ws;
    size_t o = 0;
    auto align16 = [&o]() { o = (o + 15) & ~(size_t)15; };
    int* blkcnt  = (int*)(ws + o); o += (size_t)512 * NB * 4; align16();
    int* base    = (int*)(ws + o); o += 513 * 4; align16();
    int* off     = (int*)(ws + o); o += ((size_t)N + 1) * 4; align16();
    float* dinv  = (float*)(ws + o); o += (size_t)N * 4; align16();
    int* packed  = (int*)(ws + o); o += (size_t)E * 4; align16();
    int* ssrc    = (int*)(ws + o); o += (size_t)E * 4; align16();
    __half* hsh  = (__half*)(ws + o); o += (size_t)N * 64 * 2; align16();
    __half* h1h  = (__half*)(ws + o); o += (size_t)N * 64 * 2; align16();
    __half* gsh  = hsh;  // hsh dead after agg1; reuse (N*32 fp16)
    float* outp  = (float*)d_out;

    blkhist_kernel<<<NB, 256, 0, stream>>>(dst, E, blkcnt, B);
    offsets_kernel<<<1, 512, 0, stream>>>(blkcnt, base, off, B, E, N);
    scatter2_kernel<<<NB, 256, 0, stream>>>(src, dst, blkcnt, base, packed, E,
                                            B);
    bsort_kernel<<<B, 256, 0, stream>>>(packed, base, ssrc, off, dinv, N);
    gemm1_kernel<<<(N + 511) / 512, 256, 0, stream>>>(x, W1, dinv, hsh, N);
    agg1_kernel<<<(N * 64 + 255) / 256, 256, 0, stream>>>(hsh, ssrc, off, dinv,
                                                          b1, h1h, N);
    gemm2_kernel<<<(N + 511) / 512, 256, 0, stream>>>(h1h, W2, dinv, gsh, N);
    agg2_kernel<<<(N * 32 + 255) / 256, 256, 0, stream>>>(gsh, ssrc, off, dinv,
                                                          b2, outp, N);
}

// Round 7
// 308.983 us; speedup vs baseline: 1.9714x; 1.9714x over previous
//
#include <hip/hip_runtime.h>
#include <hip/hip_fp16.h>

// GCN 2-layer. Pipeline:
//   blkhist -> offsets (decoupled, atomic-free) -> scatter2 (LDS cursors)
//   -> per-bucket LDS counting sort -> gemm1 -> gather-agg1 -> gemm2 -> gather-agg2
// R5: agg1 gather-BW bound -> fp16 tables (R6) halved gather bytes.
// R6 post-mortem: gemm2's preloaded H8 union arrays spilled (VGPR=256,
// 331 MB scratch writes, 350 us). This round: gemm2 reads __half2 directly
// in a fully-unrolled k-loop -- no register arrays, no spill.

#define BSHIFT 8
#define BNODES 256
#define NB 256  // partition blocks

union H8 {  // 8 fp16 = 16 B (static-index use only!)
    uint4 u;
    __half2 h[4];
};

// Per-block bucket histogram: blkcnt[bin*NB + blk].
__global__ __launch_bounds__(256) void blkhist_kernel(
    const int* __restrict__ dst, int E, int* __restrict__ blkcnt, int B) {
    __shared__ int h[512];
    int t = threadIdx.x, b = blockIdx.x;
    for (int i = t; i < 512; i += 256) h[i] = 0;
    __syncthreads();
    int per = (E + NB - 1) / NB;
    int lo = b * per;
    int hi = min(lo + per, E);
    for (int i = lo + t; i < hi; i += 256) atomicAdd(&h[dst[i] >> BSHIFT], 1);
    __syncthreads();
    for (int i = t; i < B; i += 256) blkcnt[i * NB + b] = h[i];
}

// One block: in-place per-bucket exclusive scan across NB blocks, then
// exclusive scan of bucket totals -> base[]. Also off[N]=E, base[B]=E.
__global__ __launch_bounds__(512) void offsets_kernel(
    int* __restrict__ blkcnt, int* __restrict__ base, int* __restrict__ off,
    int B, int E, int N) {
    __shared__ int s[512];
    int t = threadIdx.x;
    int tot = 0;
    if (t < B) {
        int* row = blkcnt + (size_t)t * NB;
        int run = 0;
#pragma unroll 4
        for (int b = 0; b < NB; b++) {
            int c = row[b];
            row[b] = run;  // within-bucket block-exclusive prefix
            run += c;
        }
        tot = run;
    }
    s[t] = tot;
    __syncthreads();
#pragma unroll
    for (int d = 1; d < 512; d <<= 1) {
        int v = (t >= d) ? s[t - d] : 0;
        __syncthreads();
        s[t] += v;
        __syncthreads();
    }
    if (t < B) base[t] = s[t] - tot;  // bucket-exclusive prefix
    if (t == 0) {
        base[B] = E;
        off[N] = E;
    }
}

// Scatter via LDS cursors seeded from precomputed bases. No global atomics.
__global__ __launch_bounds__(256) void scatter2_kernel(
    const int* __restrict__ src, const int* __restrict__ dst,
    const int* __restrict__ blkcnt, const int* __restrict__ base,
    int* __restrict__ packed, int E, int B) {
    __shared__ int cur[512];
    int t = threadIdx.x, b = blockIdx.x;
    for (int i = t; i < B; i += 256) cur[i] = base[i] + blkcnt[i * NB + b];
    __syncthreads();
    int per = (E + NB - 1) / NB;
    int lo = b * per;
    int hi = min(lo + per, E);
    for (int i = lo + t; i < hi; i += 256) {
        int d = dst[i];
        int pos = atomicAdd(&cur[d >> BSHIFT], 1);
        packed[pos] = (src[i] << BSHIFT) | (d & (BNODES - 1));
    }
}

// Per-bucket LDS counting sort -> ssrc grouped by node; also off & dinv.
__global__ __launch_bounds__(256) void bsort_kernel(
    const int* __restrict__ packed, const int* __restrict__ base,
    int* __restrict__ ssrc, int* __restrict__ off, float* __restrict__ dinv,
    int N) {
    __shared__ int s[BNODES];
    __shared__ int cur[BNODES];
    int t = threadIdx.x, b = blockIdx.x;
    s[t] = 0;
    __syncthreads();
    int lo = base[b], hi = base[b + 1];
    for (int i = lo + t; i < hi; i += 256)
        atomicAdd(&s[packed[i] & (BNODES - 1)], 1);
    __syncthreads();
    int deg = s[t];
    __syncthreads();
    s[t] = deg;
    __syncthreads();
#pragma unroll
    for (int d = 1; d < BNODES; d <<= 1) {
        int v = (t >= d) ? s[t - d] : 0;
        __syncthreads();
        s[t] += v;
        __syncthreads();
    }
    int excl = s[t] - deg;
    cur[t] = excl;
    int node = (b << BSHIFT) + t;
    if (node < N) {
        off[node] = lo + excl;
        dinv[node] = rsqrtf((float)(deg + 1));
    }
    __syncthreads();
    for (int i = lo + t; i < hi; i += 256) {
        int p = packed[i];
        int pos = atomicAdd(&cur[p & (BNODES - 1)], 1);
        ssrc[lo + pos] = p >> BSHIFT;
    }
}

// hsh = fp16((x@W1)*dinv). 2 rows/thread, W1 broadcast from LDS.
__global__ __launch_bounds__(256) void gemm1_kernel(
    const float* __restrict__ x, const float* __restrict__ W1,
    const float* __restrict__ dinv, __half* __restrict__ hsh, int N) {
    __shared__ float4 Ws[64 * 16];
    int t = threadIdx.x;
    const float4* W4 = (const float4*)W1;
    for (int i = t; i < 1024; i += 256) Ws[i] = W4[i];
    __syncthreads();
    int ra = blockIdx.x * 512 + t;
    int rb = ra + 256;
    if (ra >= N) return;
    bool hb = rb < N;
    const float4* xa = (const float4*)(x + (size_t)ra * 64);
    const float4* xb = (const float4*)(x + (size_t)rb * 64);
    float4 acc0[16], acc1[16];
#pragma unroll
    for (int j = 0; j < 16; j++) {
        acc0[j] = make_float4(0.f, 0.f, 0.f, 0.f);
        acc1[j] = make_float4(0.f, 0.f, 0.f, 0.f);
    }
    for (int k4 = 0; k4 < 16; k4++) {
        float4 x0 = xa[k4];
        float4 x1 = hb ? xb[k4] : make_float4(0.f, 0.f, 0.f, 0.f);
#pragma unroll
        for (int kk = 0; kk < 4; kk++) {
            float a0 = ((const float*)&x0)[kk];
            float a1 = ((const float*)&x1)[kk];
            const float4* wr = &Ws[(k4 * 4 + kk) * 16];
#pragma unroll
            for (int j = 0; j < 16; j++) {
                float4 w = wr[j];
                acc0[j].x += a0 * w.x; acc0[j].y += a0 * w.y;
                acc0[j].z += a0 * w.z; acc0[j].w += a0 * w.w;
                acc1[j].x += a1 * w.x; acc1[j].y += a1 * w.y;
                acc1[j].z += a1 * w.z; acc1[j].w += a1 * w.w;
            }
        }
    }
    float d0 = dinv[ra];
    uint4* ha = (uint4*)(hsh + (size_t)ra * 64);
#pragma unroll
    for (int j = 0; j < 8; j++) {
        H8 p;
        float4 v0 = acc0[2 * j], v1 = acc0[2 * j + 1];
        p.h[0] = __floats2half2_rn(v0.x * d0, v0.y * d0);
        p.h[1] = __floats2half2_rn(v0.z * d0, v0.w * d0);
        p.h[2] = __floats2half2_rn(v1.x * d0, v1.y * d0);
        p.h[3] = __floats2half2_rn(v1.z * d0, v1.w * d0);
        ha[j] = p.u;
    }
    if (hb) {
        float d1 = dinv[rb];
        uint4* hbp = (uint4*)(hsh + (size_t)rb * 64);
#pragma unroll
        for (int j = 0; j < 8; j++) {
            H8 p;
            float4 v0 = acc1[2 * j], v1 = acc1[2 * j + 1];
            p.h[0] = __floats2half2_rn(v0.x * d1, v0.y * d1);
            p.h[1] = __floats2half2_rn(v0.z * d1, v0.w * d1);
            p.h[2] = __floats2half2_rn(v1.x * d1, v1.y * d1);
            p.h[3] = __floats2half2_rn(v1.z * d1, v1.w * d1);
            hbp[j] = p.u;
        }
    }
}

// Gather-aggregate layer 1: wave per node, lane = feature (64). fp16 gathers,
// fp32 accumulate. h1h = fp16(relu(acc*dinv + b1)).
__global__ __launch_bounds__(256) void agg1_kernel(
    const __half* __restrict__ hsh, const int* __restrict__ ssrc,
    const int* __restrict__ off, const float* __restrict__ dinv,
    const float* __restrict__ b1, __half* __restrict__ h1h, int N) {
    int w = (blockIdx.x * 256 + threadIdx.x) >> 6;
    int l = threadIdx.x & 63;
    if (w >= N) return;
    float acc = __half2float(hsh[(size_t)w * 64 + l]);  // self-loop
    int lo = off[w], hi = off[w + 1];
    int e = lo;
    for (; e + 4 <= hi; e += 4) {
        int s0 = ssrc[e + 0];
        int s1 = ssrc[e + 1];
        int s2 = ssrc[e + 2];
        int s3 = ssrc[e + 3];
        float v0 = __half2float(hsh[(size_t)s0 * 64 + l]);
        float v1 = __half2float(hsh[(size_t)s1 * 64 + l]);
        float v2 = __half2float(hsh[(size_t)s2 * 64 + l]);
        float v3 = __half2float(hsh[(size_t)s3 * 64 + l]);
        acc += (v0 + v1) + (v2 + v3);
    }
    for (; e < hi; e++) {
        int s = ssrc[e];
        acc += __half2float(hsh[(size_t)s * 64 + l]);
    }
    float r = fmaxf(acc * dinv[w] + b1[l], 0.f);
    h1h[(size_t)w * 64 + l] = __float2half_rn(r);
}

// gsh = fp16((h1@W2)*dinv). ONE row/thread; __half2 loads read directly in
// the unrolled k-loop (no register arrays -> no spill; R6 lesson).
__global__ __launch_bounds__(256) void gemm2_kernel(
    const __half* __restrict__ h1h, const float* __restrict__ W2,
    const float* __restrict__ dinv, __half* __restrict__ gsh, int N) {
    __shared__ float4 Ws[64 * 8];
    int t = threadIdx.x;
    const float4* W4 = (const float4*)W2;
    for (int i = t; i < 512; i += 256) Ws[i] = W4[i];
    __syncthreads();
    int r = blockIdx.x * 256 + t;
    if (r >= N) return;
    const __half2* xr = (const __half2*)(h1h + (size_t)r * 64);
    float4 acc[8];
#pragma unroll
    for (int j = 0; j < 8; j++) acc[j] = make_float4(0.f, 0.f, 0.f, 0.f);
#pragma unroll
    for (int k2 = 0; k2 < 32; k2++) {  // feats 2*k2, 2*k2+1
        float2 f = __half22float2(xr[k2]);
        const float4* w0 = &Ws[(2 * k2) * 8];
        const float4* w1 = &Ws[(2 * k2 + 1) * 8];
#pragma unroll
        for (int j = 0; j < 8; j++) {
            float4 wa = w0[j];
            acc[j].x += f.x * wa.x; acc[j].y += f.x * wa.y;
            acc[j].z += f.x * wa.z; acc[j].w += f.x * wa.w;
        }
#pragma unroll
        for (int j = 0; j < 8; j++) {
            float4 wb = w1[j];
            acc[j].x += f.y * wb.x; acc[j].y += f.y * wb.y;
            acc[j].z += f.y * wb.z; acc[j].w += f.y * wb.w;
        }
    }
    float d0 = dinv[r];
    uint4* g = (uint4*)(gsh + (size_t)r * 32);
#pragma unroll
    for (int j = 0; j < 4; j++) {
        H8 p;
        float4 v0 = acc[2 * j], v1 = acc[2 * j + 1];
        p.h[0] = __floats2half2_rn(v0.x * d0, v0.y * d0);
        p.h[1] = __floats2half2_rn(v0.z * d0, v0.w * d0);
        p.h[2] = __floats2half2_rn(v1.x * d0, v1.y * d0);
        p.h[3] = __floats2half2_rn(v1.z * d0, v1.w * d0);
        g[j] = p.u;
    }
}

// Gather-aggregate layer 2: half-wave per node, lane = feature (32).
__global__ __launch_bounds__(256) void agg2_kernel(
    const __half* __restrict__ gsh, const int* __restrict__ ssrc,
    const int* __restrict__ off, const float* __restrict__ dinv,
    const float* __restrict__ b2, float* __restrict__ out, int N) {
    int w = (blockIdx.x * 256 + threadIdx.x) >> 5;
    int l = threadIdx.x & 31;
    if (w >= N) return;
    float acc = __half2float(gsh[(size_t)w * 32 + l]);  // self-loop
    int lo = off[w], hi = off[w + 1];
    int e = lo;
    for (; e + 4 <= hi; e += 4) {
        int s0 = ssrc[e + 0];
        int s1 = ssrc[e + 1];
        int s2 = ssrc[e + 2];
        int s3 = ssrc[e + 3];
        float v0 = __half2float(gsh[(size_t)s0 * 32 + l]);
        float v1 = __half2float(gsh[(size_t)s1 * 32 + l]);
        float v2 = __half2float(gsh[(size_t)s2 * 32 + l]);
        float v3 = __half2float(gsh[(size_t)s3 * 32 + l]);
        acc += (v0 + v1) + (v2 + v3);
    }
    for (; e < hi; e++) {
        int s = ssrc[e];
        acc += __half2float(gsh[(size_t)s * 32 + l]);
    }
    out[(size_t)w * 32 + l] = acc * dinv[w] + b2[l];
}

extern "C" void kernel_launch(void* const* d_in, const int* in_sizes, int n_in,
                              void* d_out, int out_size, void* d_ws,
                              size_t ws_size, hipStream_t stream) {
    const float* x  = (const float*)d_in[0];
    const int* ei   = (const int*)d_in[1];
    const float* W1 = (const float*)d_in[2];
    const float* b1 = (const float*)d_in[3];
    const float* W2 = (const float*)d_in[4];
    const float* b2 = (const float*)d_in[5];
    int N = in_sizes[0] / 64;
    int E = in_sizes[1] / 2;
    const int* src = ei;
    const int* dst = ei + E;
    int B = (N + BNODES - 1) >> BSHIFT;  // 391 for N=100000

    char* ws = (char*)d_ws;
    size_t o = 0;
    auto align16 = [&o]() { o = (o + 15) & ~(size_t)15; };
    int* blkcnt  = (int*)(ws + o); o += (size_t)512 * NB * 4; align16();
    int* base    = (int*)(ws + o); o += 513 * 4; align16();
    int* off     = (int*)(ws + o); o += ((size_t)N + 1) * 4; align16();
    float* dinv  = (float*)(ws + o); o += (size_t)N * 4; align16();
    int* packed  = (int*)(ws + o); o += (size_t)E * 4; align16();
    int* ssrc    = (int*)(ws + o); o += (size_t)E * 4; align16();
    __half* hsh  = (__half*)(ws + o); o += (size_t)N * 64 * 2; align16();
    __half* h1h  = (__half*)(ws + o); o += (size_t)N * 64 * 2; align16();
    __half* gsh  = hsh;  // hsh dead after agg1; reuse (N*32 fp16)
    float* outp  = (float*)d_out;

    blkhist_kernel<<<NB, 256, 0, stream>>>(dst, E, blkcnt, B);
    offsets_kernel<<<1, 512, 0, stream>>>(blkcnt, base, off, B, E, N);
    scatter2_kernel<<<NB, 256, 0, stream>>>(src, dst, blkcnt, base, packed, E,
                                            B);
    bsort_kernel<<<B, 256, 0, stream>>>(packed, base, ssrc, off, dinv, N);
    gemm1_kernel<<<(N + 511) / 512, 256, 0, stream>>>(x, W1, dinv, hsh, N);
    agg1_kernel<<<(N * 64 + 255) / 256, 256, 0, stream>>>(hsh, ssrc, off, dinv,
                                                          b1, h1h, N);
    gemm2_kernel<<<(N + 255) / 256, 256, 0, stream>>>(h1h, W2, dinv, gsh, N);
    agg2_kernel<<<(N * 32 + 255) / 256, 256, 0, stream>>>(gsh, ssrc, off, dinv,
                                                          b2, outp, N);
}

// Round 8
// 252.330 us; speedup vs baseline: 2.4140x; 1.2245x over previous
//
#include <hip/hip_runtime.h>
#include <hip/hip_fp16.h>

// GCN 2-layer. Pipeline:
//   blkhist -> rowscan -> topscan (parallel 2-level offsets) -> scatter2
//   -> per-bucket LDS counting sort -> gemm1 -> agg1 -> gemm2 -> agg2
// R5: agg gather-BW bound -> fp16 tables. R6: H8 union arrays spilled. R7:
// agg1 latency/issue bound (VALU 32%, HBM 31%). This round: half2 gathers
// with 2 nodes/wave (agg1) and 4 nodes/wave (agg2) -- 2-4x memory
// parallelism per wave; serial offsets kernel replaced by parallel scan.

#define BSHIFT 8
#define BNODES 256
#define NB 256       // partition blocks
#define BSTRIDE 512  // blkcnt row stride (bins per block row)

union H8 {  // 8 fp16 = 16 B (static-index use only! R6 lesson)
    uint4 u;
    __half2 h[4];
};

// Per-block bucket histogram: blkcnt[blk*BSTRIDE + bin] (contiguous per blk).
__global__ __launch_bounds__(256) void blkhist_kernel(
    const int* __restrict__ dst, int E, int* __restrict__ blkcnt, int B) {
    __shared__ int h[512];
    int t = threadIdx.x, b = blockIdx.x;
    for (int i = t; i < 512; i += 256) h[i] = 0;
    __syncthreads();
    int per = (E + NB - 1) / NB;
    int lo = b * per;
    int hi = min(lo + per, E);
    for (int i = lo + t; i < hi; i += 256) atomicAdd(&h[dst[i] >> BSHIFT], 1);
    __syncthreads();
    for (int i = t; i < B; i += 256) blkcnt[b * BSTRIDE + i] = h[i];
}

// One block per bin: exclusive scan across the NB block counts (in place),
// emit bin total.
__global__ __launch_bounds__(256) void rowscan_kernel(
    int* __restrict__ blkcnt, int* __restrict__ rowtot) {
    __shared__ int s[NB];
    int t = threadIdx.x, bin = blockIdx.x;
    int v = blkcnt[t * BSTRIDE + bin];
    s[t] = v;
    __syncthreads();
#pragma unroll
    for (int d = 1; d < NB; d <<= 1) {
        int u = (t >= d) ? s[t - d] : 0;
        __syncthreads();
        s[t] += u;
        __syncthreads();
    }
    blkcnt[t * BSTRIDE + bin] = s[t] - v;  // block-exclusive prefix
    if (t == NB - 1) rowtot[bin] = s[t];
}

// One block: exclusive scan of bin totals -> base[]. Also off[N]=E, base[B]=E.
__global__ __launch_bounds__(512) void topscan_kernel(
    const int* __restrict__ rowtot, int* __restrict__ base,
    int* __restrict__ off, int B, int E, int N) {
    __shared__ int s[512];
    int t = threadIdx.x;
    int v0 = (t < B) ? rowtot[t] : 0;
    s[t] = v0;
    __syncthreads();
#pragma unroll
    for (int d = 1; d < 512; d <<= 1) {
        int v = (t >= d) ? s[t - d] : 0;
        __syncthreads();
        s[t] += v;
        __syncthreads();
    }
    if (t < B) base[t] = s[t] - v0;
    if (t == 0) {
        base[B] = E;
        off[N] = E;
    }
}

// Scatter via LDS cursors seeded from precomputed bases. No global atomics.
__global__ __launch_bounds__(256) void scatter2_kernel(
    const int* __restrict__ src, const int* __restrict__ dst,
    const int* __restrict__ blkcnt, const int* __restrict__ base,
    int* __restrict__ packed, int E, int B) {
    __shared__ int cur[512];
    int t = threadIdx.x, b = blockIdx.x;
    for (int i = t; i < B; i += 256) cur[i] = base[i] + blkcnt[b * BSTRIDE + i];
    __syncthreads();
    int per = (E + NB - 1) / NB;
    int lo = b * per;
    int hi = min(lo + per, E);
    for (int i = lo + t; i < hi; i += 256) {
        int d = dst[i];
        int pos = atomicAdd(&cur[d >> BSHIFT], 1);
        packed[pos] = (src[i] << BSHIFT) | (d & (BNODES - 1));
    }
}

// Per-bucket LDS counting sort -> ssrc grouped by node; also off & dinv.
__global__ __launch_bounds__(256) void bsort_kernel(
    const int* __restrict__ packed, const int* __restrict__ base,
    int* __restrict__ ssrc, int* __restrict__ off, float* __restrict__ dinv,
    int N) {
    __shared__ int s[BNODES];
    __shared__ int cur[BNODES];
    int t = threadIdx.x, b = blockIdx.x;
    s[t] = 0;
    __syncthreads();
    int lo = base[b], hi = base[b + 1];
    for (int i = lo + t; i < hi; i += 256)
        atomicAdd(&s[packed[i] & (BNODES - 1)], 1);
    __syncthreads();
    int deg = s[t];
    __syncthreads();
    s[t] = deg;
    __syncthreads();
#pragma unroll
    for (int d = 1; d < BNODES; d <<= 1) {
        int v = (t >= d) ? s[t - d] : 0;
        __syncthreads();
        s[t] += v;
        __syncthreads();
    }
    int excl = s[t] - deg;
    cur[t] = excl;
    int node = (b << BSHIFT) + t;
    if (node < N) {
        off[node] = lo + excl;
        dinv[node] = rsqrtf((float)(deg + 1));
    }
    __syncthreads();
    for (int i = lo + t; i < hi; i += 256) {
        int p = packed[i];
        int pos = atomicAdd(&cur[p & (BNODES - 1)], 1);
        ssrc[lo + pos] = p >> BSHIFT;
    }
}

// hsh = fp16((x@W1)*dinv). 2 rows/thread, W1 broadcast from LDS.
__global__ __launch_bounds__(256) void gemm1_kernel(
    const float* __restrict__ x, const float* __restrict__ W1,
    const float* __restrict__ dinv, __half* __restrict__ hsh, int N) {
    __shared__ float4 Ws[64 * 16];
    int t = threadIdx.x;
    const float4* W4 = (const float4*)W1;
    for (int i = t; i < 1024; i += 256) Ws[i] = W4[i];
    __syncthreads();
    int ra = blockIdx.x * 512 + t;
    int rb = ra + 256;
    if (ra >= N) return;
    bool hb = rb < N;
    const float4* xa = (const float4*)(x + (size_t)ra * 64);
    const float4* xb = (const float4*)(x + (size_t)rb * 64);
    float4 acc0[16], acc1[16];
#pragma unroll
    for (int j = 0; j < 16; j++) {
        acc0[j] = make_float4(0.f, 0.f, 0.f, 0.f);
        acc1[j] = make_float4(0.f, 0.f, 0.f, 0.f);
    }
    for (int k4 = 0; k4 < 16; k4++) {
        float4 x0 = xa[k4];
        float4 x1 = hb ? xb[k4] : make_float4(0.f, 0.f, 0.f, 0.f);
#pragma unroll
        for (int kk = 0; kk < 4; kk++) {
            float a0 = ((const float*)&x0)[kk];
            float a1 = ((const float*)&x1)[kk];
            const float4* wr = &Ws[(k4 * 4 + kk) * 16];
#pragma unroll
            for (int j = 0; j < 16; j++) {
                float4 w = wr[j];
                acc0[j].x += a0 * w.x; acc0[j].y += a0 * w.y;
                acc0[j].z += a0 * w.z; acc0[j].w += a0 * w.w;
                acc1[j].x += a1 * w.x; acc1[j].y += a1 * w.y;
                acc1[j].z += a1 * w.z; acc1[j].w += a1 * w.w;
            }
        }
    }
    float d0 = dinv[ra];
    uint4* ha = (uint4*)(hsh + (size_t)ra * 64);
#pragma unroll
    for (int j = 0; j < 8; j++) {
        H8 p;
        float4 v0 = acc0[2 * j], v1 = acc0[2 * j + 1];
        p.h[0] = __floats2half2_rn(v0.x * d0, v0.y * d0);
        p.h[1] = __floats2half2_rn(v0.z * d0, v0.w * d0);
        p.h[2] = __floats2half2_rn(v1.x * d0, v1.y * d0);
        p.h[3] = __floats2half2_rn(v1.z * d0, v1.w * d0);
        ha[j] = p.u;
    }
    if (hb) {
        float d1 = dinv[rb];
        uint4* hbp = (uint4*)(hsh + (size_t)rb * 64);
#pragma unroll
        for (int j = 0; j < 8; j++) {
            H8 p;
            float4 v0 = acc1[2 * j], v1 = acc1[2 * j + 1];
            p.h[0] = __floats2half2_rn(v0.x * d1, v0.y * d1);
            p.h[1] = __floats2half2_rn(v0.z * d1, v0.w * d1);
            p.h[2] = __floats2half2_rn(v1.x * d1, v1.y * d1);
            p.h[3] = __floats2half2_rn(v1.z * d1, v1.w * d1);
            hbp[j] = p.u;
        }
    }
}

// Layer-1 aggregate: 2 nodes per wave. Lane l: node = 2*wid + (l>>5),
// feature-pair f2 = l&31 (half2). 32 lanes x 4 B = full 128 B row.
__global__ __launch_bounds__(256) void agg1_kernel(
    const __half2* __restrict__ hsh2, const int* __restrict__ ssrc,
    const int* __restrict__ off, const float* __restrict__ dinv,
    const float* __restrict__ b1, __half2* __restrict__ h1h2, int N) {
    int lane = threadIdx.x & 63;
    int wid = (blockIdx.x * 256 + threadIdx.x) >> 6;
    int node = wid * 2 + (lane >> 5);
    int f2 = lane & 31;
    if (node >= N) return;
    float2 acc0 = __half22float2(hsh2[(size_t)node * 32 + f2]);  // self-loop
    float2 acc1 = make_float2(0.f, 0.f);
    int lo = off[node], hi = off[node + 1];
    int e = lo;
    for (; e + 8 <= hi; e += 8) {
        int s0 = ssrc[e + 0], s1 = ssrc[e + 1], s2 = ssrc[e + 2],
            s3 = ssrc[e + 3];
        int s4 = ssrc[e + 4], s5 = ssrc[e + 5], s6 = ssrc[e + 6],
            s7 = ssrc[e + 7];
        float2 v0 = __half22float2(hsh2[(size_t)s0 * 32 + f2]);
        float2 v1 = __half22float2(hsh2[(size_t)s1 * 32 + f2]);
        float2 v2 = __half22float2(hsh2[(size_t)s2 * 32 + f2]);
        float2 v3 = __half22float2(hsh2[(size_t)s3 * 32 + f2]);
        float2 v4 = __half22float2(hsh2[(size_t)s4 * 32 + f2]);
        float2 v5 = __half22float2(hsh2[(size_t)s5 * 32 + f2]);
        float2 v6 = __half22float2(hsh2[(size_t)s6 * 32 + f2]);
        float2 v7 = __half22float2(hsh2[(size_t)s7 * 32 + f2]);
        acc0.x += (v0.x + v1.x) + (v2.x + v3.x);
        acc0.y += (v0.y + v1.y) + (v2.y + v3.y);
        acc1.x += (v4.x + v5.x) + (v6.x + v7.x);
        acc1.y += (v4.y + v5.y) + (v6.y + v7.y);
    }
    for (; e + 2 <= hi; e += 2) {
        int s0 = ssrc[e + 0], s1 = ssrc[e + 1];
        float2 v0 = __half22float2(hsh2[(size_t)s0 * 32 + f2]);
        float2 v1 = __half22float2(hsh2[(size_t)s1 * 32 + f2]);
        acc0.x += v0.x + v1.x;
        acc0.y += v0.y + v1.y;
    }
    if (e < hi) {
        float2 v = __half22float2(hsh2[(size_t)ssrc[e] * 32 + f2]);
        acc1.x += v.x;
        acc1.y += v.y;
    }
    float di = dinv[node];
    float2 bb = ((const float2*)b1)[f2];
    float rx = fmaxf((acc0.x + acc1.x) * di + bb.x, 0.f);
    float ry = fmaxf((acc0.y + acc1.y) * di + bb.y, 0.f);
    h1h2[(size_t)node * 32 + f2] = __floats2half2_rn(rx, ry);
}

// gsh = fp16((h1@W2)*dinv). One row/thread; direct __half2 loads (R6 lesson).
__global__ __launch_bounds__(256) void gemm2_kernel(
    const __half* __restrict__ h1h, const float* __restrict__ W2,
    const float* __restrict__ dinv, __half* __restrict__ gsh, int N) {
    __shared__ float4 Ws[64 * 8];
    int t = threadIdx.x;
    const float4* W4 = (const float4*)W2;
    for (int i = t; i < 512; i += 256) Ws[i] = W4[i];
    __syncthreads();
    int r = blockIdx.x * 256 + t;
    if (r >= N) return;
    const __half2* xr = (const __half2*)(h1h + (size_t)r * 64);
    float4 acc[8];
#pragma unroll
    for (int j = 0; j < 8; j++) acc[j] = make_float4(0.f, 0.f, 0.f, 0.f);
#pragma unroll
    for (int k2 = 0; k2 < 32; k2++) {
        float2 f = __half22float2(xr[k2]);
        const float4* w0 = &Ws[(2 * k2) * 8];
        const float4* w1 = &Ws[(2 * k2 + 1) * 8];
#pragma unroll
        for (int j = 0; j < 8; j++) {
            float4 wa = w0[j];
            acc[j].x += f.x * wa.x; acc[j].y += f.x * wa.y;
            acc[j].z += f.x * wa.z; acc[j].w += f.x * wa.w;
        }
#pragma unroll
        for (int j = 0; j < 8; j++) {
            float4 wb = w1[j];
            acc[j].x += f.y * wb.x; acc[j].y += f.y * wb.y;
            acc[j].z += f.y * wb.z; acc[j].w += f.y * wb.w;
        }
    }
    float d0 = dinv[r];
    uint4* g = (uint4*)(gsh + (size_t)r * 32);
#pragma unroll
    for (int j = 0; j < 4; j++) {
        H8 p;
        float4 v0 = acc[2 * j], v1 = acc[2 * j + 1];
        p.h[0] = __floats2half2_rn(v0.x * d0, v0.y * d0);
        p.h[1] = __floats2half2_rn(v0.z * d0, v0.w * d0);
        p.h[2] = __floats2half2_rn(v1.x * d0, v1.y * d0);
        p.h[3] = __floats2half2_rn(v1.z * d0, v1.w * d0);
        g[j] = p.u;
    }
}

// Layer-2 aggregate: 4 nodes per wave. Lane l: node = 4*wid + (l>>4),
// f2 = l&15. 16 lanes x 4 B = full 64 B row. Output fp32 float2.
__global__ __launch_bounds__(256) void agg2_kernel(
    const __half2* __restrict__ gsh2, const int* __restrict__ ssrc,
    const int* __restrict__ off, const float* __restrict__ dinv,
    const float* __restrict__ b2, float* __restrict__ out, int N) {
    int lane = threadIdx.x & 63;
    int wid = (blockIdx.x * 256 + threadIdx.x) >> 6;
    int node = wid * 4 + (lane >> 4);
    int f2 = lane & 15;
    if (node >= N) return;
    float2 acc0 = __half22float2(gsh2[(size_t)node * 16 + f2]);  // self-loop
    float2 acc1 = make_float2(0.f, 0.f);
    int lo = off[node], hi = off[node + 1];
    int e = lo;
    for (; e + 8 <= hi; e += 8) {
        int s0 = ssrc[e + 0], s1 = ssrc[e + 1], s2 = ssrc[e + 2],
            s3 = ssrc[e + 3];
        int s4 = ssrc[e + 4], s5 = ssrc[e + 5], s6 = ssrc[e + 6],
            s7 = ssrc[e + 7];
        float2 v0 = __half22float2(gsh2[(size_t)s0 * 16 + f2]);
        float2 v1 = __half22float2(gsh2[(size_t)s1 * 16 + f2]);
        float2 v2 = __half22float2(gsh2[(size_t)s2 * 16 + f2]);
        float2 v3 = __half22float2(gsh2[(size_t)s3 * 16 + f2]);
        float2 v4 = __half22float2(gsh2[(size_t)s4 * 16 + f2]);
        float2 v5 = __half22float2(gsh2[(size_t)s5 * 16 + f2]);
        float2 v6 = __half22float2(gsh2[(size_t)s6 * 16 + f2]);
        float2 v7 = __half22float2(gsh2[(size_t)s7 * 16 + f2]);
        acc0.x += (v0.x + v1.x) + (v2.x + v3.x);
        acc0.y += (v0.y + v1.y) + (v2.y + v3.y);
        acc1.x += (v4.x + v5.x) + (v6.x + v7.x);
        acc1.y += (v4.y + v5.y) + (v6.y + v7.y);
    }
    for (; e + 2 <= hi; e += 2) {
        int s0 = ssrc[e + 0], s1 = ssrc[e + 1];
        float2 v0 = __half22float2(gsh2[(size_t)s0 * 16 + f2]);
        float2 v1 = __half22float2(gsh2[(size_t)s1 * 16 + f2]);
        acc0.x += v0.x + v1.x;
        acc0.y += v0.y + v1.y;
    }
    if (e < hi) {
        float2 v = __half22float2(gsh2[(size_t)ssrc[e] * 16 + f2]);
        acc1.x += v.x;
        acc1.y += v.y;
    }
    float di = dinv[node];
    float2 bb = ((const float2*)b2)[f2];
    float2 r;
    r.x = (acc0.x + acc1.x) * di + bb.x;
    r.y = (acc0.y + acc1.y) * di + bb.y;
    ((float2*)out)[(size_t)node * 16 + f2] = r;
}

extern "C" void kernel_launch(void* const* d_in, const int* in_sizes, int n_in,
                              void* d_out, int out_size, void* d_ws,
                              size_t ws_size, hipStream_t stream) {
    const float* x  = (const float*)d_in[0];
    const int* ei   = (const int*)d_in[1];
    const float* W1 = (const float*)d_in[2];
    const float* b1 = (const float*)d_in[3];
    const float* W2 = (const float*)d_in[4];
    const float* b2 = (const float*)d_in[5];
    int N = in_sizes[0] / 64;
    int E = in_sizes[1] / 2;
    const int* src = ei;
    const int* dst = ei + E;
    int B = (N + BNODES - 1) >> BSHIFT;  // 391 for N=100000

    char* ws = (char*)d_ws;
    size_t o = 0;
    auto align16 = [&o]() { o = (o + 15) & ~(size_t)15; };
    int* blkcnt  = (int*)(ws + o); o += (size_t)NB * BSTRIDE * 4; align16();
    int* rowtot  = (int*)(ws + o); o += 512 * 4; align16();
    int* base    = (int*)(ws + o); o += 513 * 4; align16();
    int* off     = (int*)(ws + o); o += ((size_t)N + 1) * 4; align16();
    float* dinv  = (float*)(ws + o); o += (size_t)N * 4; align16();
    int* packed  = (int*)(ws + o); o += (size_t)E * 4; align16();
    int* ssrc    = (int*)(ws + o); o += (size_t)E * 4; align16();
    __half* hsh  = (__half*)(ws + o); o += (size_t)N * 64 * 2; align16();
    __half* h1h  = (__half*)(ws + o); o += (size_t)N * 64 * 2; align16();
    __half* gsh  = hsh;  // hsh dead after agg1; reuse (N*32 fp16)
    float* outp  = (float*)d_out;

    blkhist_kernel<<<NB, 256, 0, stream>>>(dst, E, blkcnt, B);
    rowscan_kernel<<<B, 256, 0, stream>>>(blkcnt, rowtot);
    topscan_kernel<<<1, 512, 0, stream>>>(rowtot, base, off, B, E, N);
    scatter2_kernel<<<NB, 256, 0, stream>>>(src, dst, blkcnt, base, packed, E,
                                            B);
    bsort_kernel<<<B, 256, 0, stream>>>(packed, base, ssrc, off, dinv, N);
    gemm1_kernel<<<(N + 511) / 512, 256, 0, stream>>>(x, W1, dinv, hsh, N);
    int w1 = (N + 1) / 2;  // 2 nodes per wave
    agg1_kernel<<<((size_t)w1 * 64 + 255) / 256, 256, 0, stream>>>(
        (const __half2*)hsh, ssrc, off, dinv, b1, (__half2*)h1h, N);
    gemm2_kernel<<<(N + 255) / 256, 256, 0, stream>>>(h1h, W2, dinv, gsh, N);
    int w2 = (N + 3) / 4;  // 4 nodes per wave
    agg2_kernel<<<((size_t)w2 * 64 + 255) / 256, 256, 0, stream>>>(
        (const __half2*)gsh, ssrc, off, dinv, b2, outp, N);
}